// Round 10
// baseline (160.499 us; speedup 1.0000x reference)
//
#include <hip/hip_runtime.h>

typedef __bf16 bf16;
typedef __bf16 bf16x8 __attribute__((ext_vector_type(8)));
typedef __bf16 bf16x4 __attribute__((ext_vector_type(4)));
typedef float f32x4 __attribute__((ext_vector_type(4)));
typedef float f32x16 __attribute__((ext_vector_type(16)));
typedef unsigned int uint2v __attribute__((ext_vector_type(2)));

#define MFMA16(a, b, c) __builtin_amdgcn_mfma_f32_16x16x32_bf16(a, b, c, 0, 0, 0)
#define MFMA32(a, b, c) __builtin_amdgcn_mfma_f32_32x32x16_bf16(a, b, c, 0, 0, 0)

// scale * log2(e) — folded into Q in GEMM1 epilogue (f32)
#define CS 0.18033688011112042f

#if __has_builtin(__builtin_amdgcn_exp2f)
#define EXP2(x) __builtin_amdgcn_exp2f(x)
#else
#define EXP2(x) exp2f(x)
#endif

// wave-local waits (gfx9 encoding: vm[3:0]|exp[6:4]|lgkm[11:8]|vm[5:4]@15:14)
#define WAIT_VM0() __builtin_amdgcn_s_waitcnt(0x0F70)   // vmcnt(0)
#define WAIT_VM3() __builtin_amdgcn_s_waitcnt(0x0F73)   // vmcnt(3)
#define WAIT_VM4() __builtin_amdgcn_s_waitcnt(0x0F74)   // vmcnt(4)
#define WAIT_VM6() __builtin_amdgcn_s_waitcnt(0x0F76)   // vmcnt(6)
#define WAIT_VM8() __builtin_amdgcn_s_waitcnt(0x0F78)   // vmcnt(8)

#define BARRIER() __builtin_amdgcn_s_barrier()
#define CFENCE() asm volatile("" ::: "memory")

// async global->LDS, 16B per lane; LDS dest must be lane-linear per wave.
__device__ __forceinline__ void load_lds16(const bf16* g, bf16* l) {
    __builtin_amdgcn_global_load_lds(
        (const __attribute__((address_space(1))) unsigned int*)g,
        (__attribute__((address_space(3))) unsigned int*)l, 16, 0, 0);
}

#if __has_builtin(__builtin_amdgcn_permlane32_swap)
// v_permlane32_swap_b32 (VALU pipe) replaces ds_bpermute for the
// lane[i]<->lane[i+32] exchange (proven round 4: attn 59 -> 49 us):
//   ret0[l] = l<32 ? a[l] : b[l-32];  ret1[l] = l<32 ? a[l+32] : b[l]
__device__ __forceinline__ bf16x8 build_bfrag(bf16x4 plo, bf16x4 phi, int /*h*/) {
    union { bf16x4 b; unsigned int i[2]; } ul, uh;
    ul.b = plo; uh.b = phi;
    uint2v r0 = __builtin_amdgcn_permlane32_swap(ul.i[0], uh.i[0], false, false);
    uint2v r1 = __builtin_amdgcn_permlane32_swap(ul.i[1], uh.i[1], false, false);
    union { unsigned int i[4]; bf16x8 b; } ub;
    ub.i[0] = r0[0]; ub.i[1] = r1[0]; ub.i[2] = r0[1]; ub.i[3] = r1[1];
    return ub.b;
}

__device__ __forceinline__ float sum_halves(float x) {
    union { float f; unsigned int u; } a; a.f = x;
    uint2v r = __builtin_amdgcn_permlane32_swap(a.u, a.u, false, false);
    union { unsigned int u; float f; } b0, b1;
    b0.u = r[0]; b1.u = r[1];
    return b0.f + b1.f;
}
#else
__device__ __forceinline__ bf16x4 shfl_xor32_b64(bf16x4 v) {
    union { bf16x4 b; int i[2]; } u;
    u.b = v;
    u.i[0] = __shfl_xor(u.i[0], 32, 64);
    u.i[1] = __shfl_xor(u.i[1], 32, 64);
    return u.b;
}
__device__ __forceinline__ bf16x8 build_bfrag(bf16x4 plo, bf16x4 phi, int h) {
    bf16x4 xlo = shfl_xor32_b64(plo);
    bf16x4 xhi = shfl_xor32_b64(phi);
    bf16x4 lo4 = h ? xhi : plo;
    bf16x4 hi4 = h ? phi : xlo;
    bf16x8 bb;
#pragma unroll
    for (int i = 0; i < 4; ++i) { bb[i] = lo4[i]; bb[4 + i] = hi4[i]; }
    return bb;
}
__device__ __forceinline__ float sum_halves(float x) {
    return x + __shfl_xor(x, 32, 64);
}
#endif

// ---------------------------------------------------------------------------
// Fused prep: one dispatch replaces {f32->bf16 convert, w_qkv transpose,
// w_out transpose}. Block-uniform job decode from blockIdx.x ranges.
// ---------------------------------------------------------------------------
__global__ __launch_bounds__(256) void prep_kernel(const float* __restrict__ x,
                                                   const float* __restrict__ w_qkv,
                                                   const float* __restrict__ w_out,
                                                   bf16* __restrict__ xb,
                                                   bf16* __restrict__ wqkvT,
                                                   bf16* __restrict__ woutT) {
    __shared__ float tile[32][33];
    int bid = blockIdx.x, t = threadIdx.x;
    if (bid < 4096) {                   // x f32 -> bf16
        int i = (bid * 256 + t) * 4;
        float4 v = *(const float4*)&x[i];
        bf16x4 o = {(bf16)v.x, (bf16)v.y, (bf16)v.z, (bf16)v.w};
        *(bf16x4*)&xb[i] = o;
        return;
    }
    const float* in; bf16* out; int C, bx, by;
    if (bid < 4864) { int b2 = bid - 4096; in = w_qkv; out = wqkvT; C = 1536; bx = b2 % 48; by = b2 / 48; }
    else            { int b3 = bid - 4864; in = w_out; out = woutT; C = 512;  bx = b3 & 15; by = b3 >> 4; }
    const int R = 512;
    int tx = t & 31, ty = t >> 5;
    int c0 = bx * 32, r0 = by * 32;
#pragma unroll
    for (int i = ty; i < 32; i += 8)
        tile[i][tx] = in[(size_t)(r0 + i) * C + c0 + tx];
    __syncthreads();
#pragma unroll
    for (int i = ty; i < 32; i += 8)
        out[(size_t)(c0 + i) * R + r0 + tx] = (bf16)tile[tx][i];
}

// ---------------------------------------------------------------------------
// C[M][N] = A[M][K] @ Bt[N][K]^T, bf16 in, fp32 acc. BM=MT*32, BN=128,
// BK template param. 2-phase double-buffered LDS pipeline + XCD-chunked
// block swizzle.
// v14: gemm1 uses MT=2 (BM=64) + BK=32 -> 24KB LDS, grid 1536 -> 6 blocks/CU
// (was grid-limited to 3): 24 waves/CU, barrier drains overlap across 6
// independent blocks. B-panel L2 re-reads double but stay L2-resident.
// MODE 1 (QKV GEMM): cols<512 scaled by CS, bf16 out; V-blocks (n0>=1024)
//   written DIRECTLY TRANSPOSED into vt[bh][d][n] (round-8 win).
// MODE 2 (out proj): +bias, f32 out.
// ---------------------------------------------------------------------------
template <int MT, int BK, int MODE, typename OutT>
__global__ __launch_bounds__(256, 2)
void gemm_bt_kernel(const bf16* __restrict__ A,
                    const bf16* __restrict__ Bt,
                    const float* __restrict__ bias,
                    OutT* __restrict__ C,
                    bf16* __restrict__ vtout,
                    int M, int N, int K) {
    const int BM = MT * 32;
    const int CPR = BK / 8;                 // 16B chunks per row
    const int ASZ = BM * BK, BSZ = 128 * BK;
    const int ALD = ASZ / 2048, BLD = BSZ / 2048;   // loads/thread/stage
    __shared__ bf16 As[2 * ASZ];
    __shared__ bf16 Bs[2 * BSZ];
    int t = threadIdx.x;
    int lane = t & 63, w = t >> 6;
    int wr = w >> 1, wc = w & 1;
    int quad = lane >> 4, r16 = lane & 15;

    // XCD-chunked swizzle (grid total divisible by 8)
    int lin = blockIdx.y * gridDim.x + blockIdx.x;
    int cpx = (gridDim.x * gridDim.y) >> 3;
    int nl = (lin & 7) * cpx + (lin >> 3);
    int bx = nl % gridDim.x, by = nl / gridDim.x;
    int m0 = by * BM, n0 = bx * 128;

    const f32x4 fzero = {0.f, 0.f, 0.f, 0.f};
    f32x4 acc[MT][4];
#pragma unroll
    for (int i = 0; i < MT; ++i)
#pragma unroll
        for (int j = 0; j < 4; ++j) acc[i][j] = fzero;

    const bf16* ap[ALD]; bf16* ad[ALD];
    const bf16* bp[BLD]; bf16* bd[BLD];
#pragma unroll
    for (int i = 0; i < ALD; ++i) {
        int ci = i * 256 + t;
        int row = ci / CPR, cp = ci % CPR, cc = cp ^ (row & (CPR - 1));
        ap[i] = &A[(size_t)(m0 + row) * K + cc * 8];
        ad[i] = &As[ci * 8];
    }
#pragma unroll
    for (int i = 0; i < BLD; ++i) {
        int ci = i * 256 + t;
        int row = ci / CPR, cp = ci % CPR, cc = cp ^ (row & (CPR - 1));
        bp[i] = &Bt[(size_t)(n0 + row) * K + cc * 8];
        bd[i] = &Bs[ci * 8];
    }

    auto stage = [&](int par) {
#pragma unroll
        for (int i = 0; i < ALD; ++i) { load_lds16(ap[i], ad[i] + par * ASZ); ap[i] += BK; }
#pragma unroll
        for (int i = 0; i < BLD; ++i) { load_lds16(bp[i], bd[i] + par * BSZ); bp[i] += BK; }
    };

    stage(0);                       // prologue: tile 0 -> buf 0
    int nk = K / BK;
    for (int kk = 0; kk < nk; ++kk) {
        if (kk + 1 < nk) {
            stage((kk + 1) & 1);    // tile k+1 in flight behind compute k
            if constexpr (ALD + BLD == 3) WAIT_VM3();
            else if constexpr (ALD + BLD == 4) WAIT_VM4();
            else if constexpr (ALD + BLD == 6) WAIT_VM6();
            else WAIT_VM8();
        } else {
            WAIT_VM0();
        }
        CFENCE(); BARRIER(); CFENCE();   // all waves' tile-k portions landed

        const bf16* Asb = &As[(kk & 1) * ASZ];
        const bf16* Bsb = &Bs[(kk & 1) * BSZ];
#pragma unroll
        for (int ks = 0; ks < BK / 32; ++ks) {
            bf16x8 af[MT], bfr[4];
            int swz = (ks * 4 + quad) ^ (r16 & (CPR - 1));
#pragma unroll
            for (int mt = 0; mt < MT; ++mt)
                af[mt] = *(const bf16x8*)&Asb[(wr * (BM / 2) + mt * 16 + r16) * BK + swz * 8];
#pragma unroll
            for (int nt = 0; nt < 4; ++nt)
                bfr[nt] = *(const bf16x8*)&Bsb[(wc * 64 + nt * 16 + r16) * BK + swz * 8];
#pragma unroll
            for (int mt = 0; mt < MT; ++mt)
#pragma unroll
                for (int nt = 0; nt < 4; ++nt)
                    acc[mt][nt] = MFMA16(af[mt], bfr[nt], acc[mt][nt]);
        }
        if (kk + 1 < nk) { CFENCE(); BARRIER(); CFENCE(); }  // buf free for kk+2
    }
#pragma unroll
    for (int mt = 0; mt < MT; ++mt)
#pragma unroll
        for (int nt = 0; nt < 4; ++nt) {
            int col = n0 + wc * 64 + nt * 16 + r16;
            int row0 = m0 + wr * (BM / 2) + mt * 16 + quad * 4;
            if (MODE == 1 && n0 >= 1024) {
                // V-block: write transposed into vt[bh][d][n]
                int dg = col - 1024, hh = dg >> 6, d = dg & 63;
                int bb = row0 >> 11, n = row0 & 2047;
                bf16x4 o;
#pragma unroll
                for (int r = 0; r < 4; ++r) o[r] = (bf16)acc[mt][nt][r];
                *(bf16x4*)&vtout[((size_t)((bb << 3) | hh) * 64 + d) * 2048 + n] = o;
            } else {
#pragma unroll
                for (int r = 0; r < 4; ++r) {
                    float v = acc[mt][nt][r];
                    if (MODE == 1 && n0 < 512) v *= CS;
                    if (MODE == 2) v += bias[col];
                    C[(size_t)(row0 + r) * N + col] = (OutT)v;
                }
            }
        }
}

// ---------------------------------------------------------------------------
// Flash attention v14 = v8 exactly (proven 48.4-50.6 us): barrier-free
// per-wave streaming, SW-pipelined private double-buffered LDS staging,
// vmcnt(8) counted wait, permlane32_swap bfrag. setprio REVERTED (round 9:
// attn 50.6->52.8 — no wave role-diversity here, all waves run the identical
// loop, so prio boosts just starve twins; matches m190's null/negative).
// ---------------------------------------------------------------------------
__global__ __launch_bounds__(128, 2) void attn_kernel(const bf16* __restrict__ qkv,
                                                      const bf16* __restrict__ vt,
                                                      bf16* __restrict__ out) {
    __shared__ __align__(16) char smemraw[32768];
    bf16* stage = (bf16*)smemraw;       // [2 waves][2 bufs][4096 elems]

    int t = threadIdx.x;
    int lane = t & 63, w = t >> 6;      // w in {0,1}
    int h = lane >> 5, q = lane & 31;
    int bh = blockIdx.y, b = bh >> 3, hd = bh & 7;
    int qb = blockIdx.x * 64;

    // Q fragments for both subtiles: lane holds Q[qb+sub*32+q][s*16+h*8+j]
    bf16x8 qf[2][4];
#pragma unroll
    for (int sub = 0; sub < 2; ++sub) {
        size_t qoff = (size_t)(b * 2048 + qb + sub * 32 + q) * 1536 + hd * 64;
#pragma unroll
        for (int s = 0; s < 4; ++s)
            qf[sub][s] = *(const bf16x8*)&qkv[qoff + s * 16 + h * 8];
    }

    f32x16 o_acc[2][2];
#pragma unroll
    for (int sub = 0; sub < 2; ++sub)
#pragma unroll
        for (int db = 0; db < 2; ++db)
#pragma unroll
            for (int i = 0; i < 16; ++i) o_acc[sub][db][i] = 0.f;
    float psum[2] = {0.f, 0.f};

    bf16* base = stage + w * 8192;      // this wave's two buffers

    // staging pointers (advance by constant stride) + LDS offsets in-buffer
    const bf16* kp[4]; const bf16* vp[4];
    int kdo[4], vdo[4];
#pragma unroll
    for (int rdd = 0; rdd < 4; ++rdd) {
        int ciK = rdd * 64 + lane;
        int rowK = ciK >> 3, ccK = (ciK & 7) ^ (rowK & 7);
        kp[rdd] = &qkv[(size_t)(b * 2048 + w * 1024 + rowK) * 1536 + 512 + hd * 64 + ccK * 8];
        kdo[rdd] = ciK * 8;
        int ciV = rdd * 64 + lane;
        int rowV = ciV >> 2, ccV = (ciV & 3) ^ (rowV & 3);
        vp[rdd] = &vt[(size_t)(bh * 64 + rowV) * 2048 + w * 1024 + ccV * 8];
        vdo[rdd] = 2048 + ciV * 8;
    }

    // prologue: stage tile 0 into buf 0
#pragma unroll
    for (int rdd = 0; rdd < 4; ++rdd) {
        load_lds16(kp[rdd], base + kdo[rdd]);  kp[rdd] += (size_t)32 * 1536;
        load_lds16(vp[rdd], base + vdo[rdd]);  vp[rdd] += 32;
    }

    for (int it = 0; it < 32; ++it) {
        const bf16* Ks = base + (it & 1) * 4096;   // [32][64]
        const bf16* Vs = Ks + 2048;                // [64][32]
        if (it < 31) {
            bf16* nb = base + ((it + 1) & 1) * 4096;
#pragma unroll
            for (int rdd = 0; rdd < 4; ++rdd) {
                load_lds16(kp[rdd], nb + kdo[rdd]);  kp[rdd] += (size_t)32 * 1536;
                load_lds16(vp[rdd], nb + vdo[rdd]);  vp[rdd] += 32;
            }
            WAIT_VM8();    // tile `it` resident; tile it+1 still in flight
        } else {
            WAIT_VM0();    // final tile resident
        }

        // K fragments (shared by both q-subtiles): A-row m = q (kv-local)
        bf16x8 kf[4];
#pragma unroll
        for (int s = 0; s < 4; ++s) {
            int cp = (s * 2 + h) ^ (q & 7);
            kf[s] = *(const bf16x8*)&Ks[q * 64 + cp * 8];
        }
        // V fragments (shared by both q-subtiles): A-row d = db*32+q
        bf16x8 vf[2][2];
#pragma unroll
        for (int kstep = 0; kstep < 2; ++kstep)
#pragma unroll
            for (int db = 0; db < 2; ++db) {
                int cp = (kstep * 2 + h) ^ (q & 3);
                vf[kstep][db] = *(const bf16x8*)&Vs[(db * 32 + q) * 32 + cp * 8];
            }

#pragma unroll
        for (int sub = 0; sub < 2; ++sub) {
            f32x16 sacc;
#pragma unroll
            for (int i = 0; i < 16; ++i) sacc[i] = 0.f;
#pragma unroll
            for (int s = 0; s < 4; ++s)
                sacc = MFMA32(kf[s], qf[sub][s], sacc);

            // P = exp2(S); psum; build PV B-frags
            bf16x4 pk[4];
            float ps0 = 0.f, ps1 = 0.f, ps2 = 0.f, ps3 = 0.f;
#pragma unroll
            for (int i = 0; i < 4; ++i) {
                float p0 = EXP2(sacc[i]);
                float p1 = EXP2(sacc[4 + i]);
                float p2 = EXP2(sacc[8 + i]);
                float p3 = EXP2(sacc[12 + i]);
                ps0 += p0; ps1 += p1; ps2 += p2; ps3 += p3;
                pk[0][i] = (bf16)p0; pk[1][i] = (bf16)p1;
                pk[2][i] = (bf16)p2; pk[3][i] = (bf16)p3;
            }
            psum[sub] += (ps0 + ps1) + (ps2 + ps3);
            bf16x8 bfr0 = build_bfrag(pk[0], pk[1], h);
            bf16x8 bfr1 = build_bfrag(pk[2], pk[3], h);

            // O^T += V^T . P^T
#pragma unroll
            for (int db = 0; db < 2; ++db) {
                o_acc[sub][db] = MFMA32(vf[0][db], bfr0, o_acc[sub][db]);
                o_acc[sub][db] = MFMA32(vf[1][db], bfr1, o_acc[sub][db]);
            }
        }
    }

    // per-q l for this wave's kv half (sum both lane-halves)
    float l_own[2];
#pragma unroll
    for (int sub = 0; sub < 2; ++sub)
        l_own[sub] = sum_halves(psum[sub]);

    // ---- 2-way merge through LDS (overlays stage buffers; barriered) ----
    __syncthreads();
    float* Of = (float*)smemraw;               // [64 q][68]
    float* Lf = (float*)(smemraw + 17408);     // [64]

    if (w == 1) {
#pragma unroll
        for (int sub = 0; sub < 2; ++sub) {
#pragma unroll
            for (int db = 0; db < 2; ++db)
#pragma unroll
                for (int r = 0; r < 16; ++r) {
                    int d = db * 32 + (r & 3) + 8 * (r >> 2) + 4 * h;
                    Of[(sub * 32 + q) * 68 + d] = o_acc[sub][db][r];
                }
            if (h == 0) Lf[sub * 32 + q] = l_own[sub];
        }
    }
    __syncthreads();
    if (w == 0) {
#pragma unroll
        for (int sub = 0; sub < 2; ++sub) {
#pragma unroll
            for (int db = 0; db < 2; ++db)
#pragma unroll
                for (int r = 0; r < 16; ++r) {
                    int d = db * 32 + (r & 3) + 8 * (r >> 2) + 4 * h;
                    Of[(sub * 32 + q) * 68 + d] += o_acc[sub][db][r];
                }
            if (h == 0) Lf[sub * 32 + q] += l_own[sub];
        }
    }
    __syncthreads();

    // normalize + coalesced store: 128 threads, each 1 half-row (32 elems)
    {
        int row = t >> 1, half = t & 1;
        float linv = 1.f / Lf[row];
        const float* src = &Of[row * 68 + half * 32];
        bf16* dst = &out[(size_t)(b * 2048 + qb + row) * 512 + hd * 64 + half * 32];
#pragma unroll
        for (int i = 0; i < 4; ++i) {
            f32x4 a = *(const f32x4*)&src[i * 8];
            f32x4 c = *(const f32x4*)&src[i * 8 + 4];
            bf16x8 o8;
#pragma unroll
            for (int j = 0; j < 4; ++j) {
                o8[j] = (bf16)(a[j] * linv);
                o8[4 + j] = (bf16)(c[j] * linv);
            }
            *(bf16x8*)&dst[i * 8] = o8;
        }
    }
}

// ---------------------------------------------------------------------------
extern "C" void kernel_launch(void* const* d_in, const int* in_sizes, int n_in,
                              void* d_out, int out_size, void* d_ws, size_t ws_size,
                              hipStream_t stream) {
    const float* x     = (const float*)d_in[0];   // [4*2048][512] f32
    const float* w_qkv = (const float*)d_in[1];   // [512][1536]   f32
    const float* w_out = (const float*)d_in[2];   // [512][512]    f32
    const float* b_out = (const float*)d_in[3];   // [512]         f32
    float* out = (float*)d_out;                   // [4*2048][512] f32

    char* ws = (char*)d_ws;
    size_t off = 0;
    bf16* xb    = (bf16*)(ws + off); off += (size_t)8192 * 512 * 2;        // 8 MB
    bf16* wqkvT = (bf16*)(ws + off); off += (size_t)1536 * 512 * 2;        // 1.5 MB
    bf16* woutT = (bf16*)(ws + off); off += (size_t)512 * 512 * 2;         // 0.5 MB
    bf16* qkv   = (bf16*)(ws + off); off += (size_t)8192 * 1536 * 2;       // 24 MB
    bf16* vt    = (bf16*)(ws + off); off += (size_t)32 * 64 * 2048 * 2;    // 8 MB
    bf16* attn  = (bf16*)(ws + off);                                       // 8 MB

    // fused prep: convert x + both weight transposes
    prep_kernel<<<5120, 256, 0, stream>>>(x, w_qkv, w_out, xb, wqkvT, woutT);
    // QKV GEMM, 64x128 tile, BK=32 (24KB LDS), grid 1536 -> 6 blocks/CU;
    // V written directly transposed to vt
    gemm_bt_kernel<2, 32, 1, bf16><<<dim3(12, 128), 256, 0, stream>>>(
        xb, wqkvT, nullptr, qkv, vt, 8192, 1536, 512);
    attn_kernel<<<dim3(32, 32), 128, 0, stream>>>(qkv, vt, attn);
    // out proj, BM=64, BK=64, grid 512, +bias, f32 out
    gemm_bt_kernel<2, 64, 2, float><<<dim3(4, 128), 256, 0, stream>>>(
        attn, woutT, b_out, out, nullptr, 8192, 512, 512);
}

// Round 11
// 150.637 us; speedup vs baseline: 1.0655x; 1.0655x over previous
//
#include <hip/hip_runtime.h>

typedef __bf16 bf16;
typedef __bf16 bf16x8 __attribute__((ext_vector_type(8)));
typedef __bf16 bf16x4 __attribute__((ext_vector_type(4)));
typedef float f32x4 __attribute__((ext_vector_type(4)));
typedef float f32x16 __attribute__((ext_vector_type(16)));
typedef unsigned int uint2v __attribute__((ext_vector_type(2)));

#define MFMA16(a, b, c) __builtin_amdgcn_mfma_f32_16x16x32_bf16(a, b, c, 0, 0, 0)
#define MFMA32(a, b, c) __builtin_amdgcn_mfma_f32_32x32x16_bf16(a, b, c, 0, 0, 0)

// scale * log2(e) — folded into Q in GEMM1 epilogue (f32)
#define CS 0.18033688011112042f

#if __has_builtin(__builtin_amdgcn_exp2f)
#define EXP2(x) __builtin_amdgcn_exp2f(x)
#else
#define EXP2(x) exp2f(x)
#endif

// wave-local waits (gfx9 encoding: vm[3:0]|exp[6:4]|lgkm[11:8]|vm[5:4]@15:14)
#define WAIT_VM0() __builtin_amdgcn_s_waitcnt(0x0F70)   // vmcnt(0)
#define WAIT_VM3() __builtin_amdgcn_s_waitcnt(0x0F73)   // vmcnt(3)
#define WAIT_VM4() __builtin_amdgcn_s_waitcnt(0x0F74)   // vmcnt(4)
#define WAIT_VM6() __builtin_amdgcn_s_waitcnt(0x0F76)   // vmcnt(6)
#define WAIT_VM8() __builtin_amdgcn_s_waitcnt(0x0F78)   // vmcnt(8)

#define BARRIER() __builtin_amdgcn_s_barrier()
#define CFENCE() asm volatile("" ::: "memory")

// async global->LDS, 16B per lane; LDS dest must be lane-linear per wave.
__device__ __forceinline__ void load_lds16(const bf16* g, bf16* l) {
    __builtin_amdgcn_global_load_lds(
        (const __attribute__((address_space(1))) unsigned int*)g,
        (__attribute__((address_space(3))) unsigned int*)l, 16, 0, 0);
}

#if __has_builtin(__builtin_amdgcn_permlane32_swap)
// v_permlane32_swap_b32 (VALU pipe) replaces ds_bpermute for the
// lane[i]<->lane[i+32] exchange (proven round 4: attn 59 -> 49 us):
//   ret0[l] = l<32 ? a[l] : b[l-32];  ret1[l] = l<32 ? a[l+32] : b[l]
__device__ __forceinline__ bf16x8 build_bfrag(bf16x4 plo, bf16x4 phi, int /*h*/) {
    union { bf16x4 b; unsigned int i[2]; } ul, uh;
    ul.b = plo; uh.b = phi;
    uint2v r0 = __builtin_amdgcn_permlane32_swap(ul.i[0], uh.i[0], false, false);
    uint2v r1 = __builtin_amdgcn_permlane32_swap(ul.i[1], uh.i[1], false, false);
    union { unsigned int i[4]; bf16x8 b; } ub;
    ub.i[0] = r0[0]; ub.i[1] = r1[0]; ub.i[2] = r0[1]; ub.i[3] = r1[1];
    return ub.b;
}

__device__ __forceinline__ float sum_halves(float x) {
    union { float f; unsigned int u; } a; a.f = x;
    uint2v r = __builtin_amdgcn_permlane32_swap(a.u, a.u, false, false);
    union { unsigned int u; float f; } b0, b1;
    b0.u = r[0]; b1.u = r[1];
    return b0.f + b1.f;
}
#else
__device__ __forceinline__ bf16x4 shfl_xor32_b64(bf16x4 v) {
    union { bf16x4 b; int i[2]; } u;
    u.b = v;
    u.i[0] = __shfl_xor(u.i[0], 32, 64);
    u.i[1] = __shfl_xor(u.i[1], 32, 64);
    return u.b;
}
__device__ __forceinline__ bf16x8 build_bfrag(bf16x4 plo, bf16x4 phi, int h) {
    bf16x4 xlo = shfl_xor32_b64(plo);
    bf16x4 xhi = shfl_xor32_b64(phi);
    bf16x4 lo4 = h ? xhi : plo;
    bf16x4 hi4 = h ? phi : xlo;
    bf16x8 bb;
#pragma unroll
    for (int i = 0; i < 4; ++i) { bb[i] = lo4[i]; bb[4 + i] = hi4[i]; }
    return bb;
}
__device__ __forceinline__ float sum_halves(float x) {
    return x + __shfl_xor(x, 32, 64);
}
#endif

// ---------------------------------------------------------------------------
// Fused prep: one dispatch replaces {f32->bf16 convert, w_qkv transpose,
// w_out transpose}. Block-uniform job decode from blockIdx.x ranges.
// ---------------------------------------------------------------------------
__global__ __launch_bounds__(256) void prep_kernel(const float* __restrict__ x,
                                                   const float* __restrict__ w_qkv,
                                                   const float* __restrict__ w_out,
                                                   bf16* __restrict__ xb,
                                                   bf16* __restrict__ wqkvT,
                                                   bf16* __restrict__ woutT) {
    __shared__ float tile[32][33];
    int bid = blockIdx.x, t = threadIdx.x;
    if (bid < 4096) {                   // x f32 -> bf16
        int i = (bid * 256 + t) * 4;
        float4 v = *(const float4*)&x[i];
        bf16x4 o = {(bf16)v.x, (bf16)v.y, (bf16)v.z, (bf16)v.w};
        *(bf16x4*)&xb[i] = o;
        return;
    }
    const float* in; bf16* out; int C, bx, by;
    if (bid < 4864) { int b2 = bid - 4096; in = w_qkv; out = wqkvT; C = 1536; bx = b2 % 48; by = b2 / 48; }
    else            { int b3 = bid - 4864; in = w_out; out = woutT; C = 512;  bx = b3 & 15; by = b3 >> 4; }
    const int R = 512;
    int tx = t & 31, ty = t >> 5;
    int c0 = bx * 32, r0 = by * 32;
#pragma unroll
    for (int i = ty; i < 32; i += 8)
        tile[i][tx] = in[(size_t)(r0 + i) * C + c0 + tx];
    __syncthreads();
#pragma unroll
    for (int i = ty; i < 32; i += 8)
        out[(size_t)(c0 + i) * R + r0 + tx] = (bf16)tile[tx][i];
}

// ---------------------------------------------------------------------------
// C[M][N] = A[M][K] @ Bt[N][K]^T, bf16 in, fp32 acc. BM=MT*32, BN=128,
// BK and NBUF template params. NBUF-deep LDS pipeline with counted vmcnt
// (tile k+NBUF-1 issues while k computes; never drains mid-loop) +
// XCD-chunked block swizzle.
// Round 8-10 tile-space result: gemm1 optimum is MT=4/BK=32 (16-MFMA cluster
// between barriers @ 3 blocks/CU; MT=2's 8-MFMA cluster regressed 11%:
// barrier amortization beats occupancy). v15 adds NBUF=3 for gemm1: 48KB LDS
// still fits 3 blocks/CU (grid-capped), 2 tiles in flight hides L2 latency.
// MODE 1 (QKV GEMM): cols<512 scaled by CS, bf16 out; V-blocks (n0>=1024)
//   written DIRECTLY TRANSPOSED into vt[bh][d][n] (round-8 win).
// MODE 2 (out proj): +bias, f32 out.
// ---------------------------------------------------------------------------
template <int MT, int BK, int NBUF, int MODE, typename OutT>
__global__ __launch_bounds__(256, 2)
void gemm_bt_kernel(const bf16* __restrict__ A,
                    const bf16* __restrict__ Bt,
                    const float* __restrict__ bias,
                    OutT* __restrict__ C,
                    bf16* __restrict__ vtout,
                    int M, int N, int K) {
    const int BM = MT * 32;
    const int CPR = BK / 8;                 // 16B chunks per row
    const int ASZ = BM * BK, BSZ = 128 * BK;
    const int ALD = ASZ / 2048, BLD = BSZ / 2048;   // loads/thread/stage
    const int L = ALD + BLD;
    __shared__ bf16 As[NBUF * ASZ];
    __shared__ bf16 Bs[NBUF * BSZ];
    int t = threadIdx.x;
    int lane = t & 63, w = t >> 6;
    int wr = w >> 1, wc = w & 1;
    int quad = lane >> 4, r16 = lane & 15;

    // XCD-chunked swizzle (grid total divisible by 8)
    int lin = blockIdx.y * gridDim.x + blockIdx.x;
    int cpx = (gridDim.x * gridDim.y) >> 3;
    int nl = (lin & 7) * cpx + (lin >> 3);
    int bx = nl % gridDim.x, by = nl / gridDim.x;
    int m0 = by * BM, n0 = bx * 128;

    const f32x4 fzero = {0.f, 0.f, 0.f, 0.f};
    f32x4 acc[MT][4];
#pragma unroll
    for (int i = 0; i < MT; ++i)
#pragma unroll
        for (int j = 0; j < 4; ++j) acc[i][j] = fzero;

    const bf16* ap[ALD]; bf16* ad[ALD];
    const bf16* bp[BLD]; bf16* bd[BLD];
#pragma unroll
    for (int i = 0; i < ALD; ++i) {
        int ci = i * 256 + t;
        int row = ci / CPR, cp = ci % CPR, cc = cp ^ (row & (CPR - 1));
        ap[i] = &A[(size_t)(m0 + row) * K + cc * 8];
        ad[i] = &As[ci * 8];
    }
#pragma unroll
    for (int i = 0; i < BLD; ++i) {
        int ci = i * 256 + t;
        int row = ci / CPR, cp = ci % CPR, cc = cp ^ (row & (CPR - 1));
        bp[i] = &Bt[(size_t)(n0 + row) * K + cc * 8];
        bd[i] = &Bs[ci * 8];
    }

    auto stage = [&](int par) {
#pragma unroll
        for (int i = 0; i < ALD; ++i) { load_lds16(ap[i], ad[i] + par * ASZ); ap[i] += BK; }
#pragma unroll
        for (int i = 0; i < BLD; ++i) { load_lds16(bp[i], bd[i] + par * BSZ); bp[i] += BK; }
    };

    int nk = K / BK;
#pragma unroll
    for (int p = 0; p < NBUF - 1; ++p) stage(p);    // prologue
    int cur = 0, nxt = NBUF - 1;
    for (int kk = 0; kk < nk; ++kk) {
        int rem = nk - 1 - kk;
        if (rem >= NBUF - 1) {
            stage(nxt);                 // tile kk+NBUF-1 in flight behind kk
            nxt = (nxt + 1 == NBUF) ? 0 : nxt + 1;
            // wait for tile kk: L*(NBUF-1) loads may remain outstanding
            if constexpr (L * (NBUF - 1) == 3) WAIT_VM3();
            else if constexpr (L * (NBUF - 1) == 4) WAIT_VM4();
            else if constexpr (L * (NBUF - 1) == 6) WAIT_VM6();
            else WAIT_VM8();
        } else if (NBUF == 3 && rem == 1) {
            // no new stage issued; only tile kk+1's L loads outstanding
            if constexpr (L == 3) WAIT_VM3(); else WAIT_VM4();
        } else {
            WAIT_VM0();
        }
        CFENCE(); BARRIER(); CFENCE();   // all waves' tile-kk portions landed

        const bf16* Asb = &As[cur * ASZ];
        const bf16* Bsb = &Bs[cur * BSZ];
#pragma unroll
        for (int ks = 0; ks < BK / 32; ++ks) {
            bf16x8 af[MT], bfr[4];
            int swz = (ks * 4 + quad) ^ (r16 & (CPR - 1));
#pragma unroll
            for (int mt = 0; mt < MT; ++mt)
                af[mt] = *(const bf16x8*)&Asb[(wr * (BM / 2) + mt * 16 + r16) * BK + swz * 8];
#pragma unroll
            for (int nt = 0; nt < 4; ++nt)
                bfr[nt] = *(const bf16x8*)&Bsb[(wc * 64 + nt * 16 + r16) * BK + swz * 8];
#pragma unroll
            for (int mt = 0; mt < MT; ++mt)
#pragma unroll
                for (int nt = 0; nt < 4; ++nt)
                    acc[mt][nt] = MFMA16(af[mt], bfr[nt], acc[mt][nt]);
        }
        cur = (cur + 1 == NBUF) ? 0 : cur + 1;
        if (kk + 1 < nk) { CFENCE(); BARRIER(); CFENCE(); }  // buf reusable
    }
#pragma unroll
    for (int mt = 0; mt < MT; ++mt)
#pragma unroll
        for (int nt = 0; nt < 4; ++nt) {
            int col = n0 + wc * 64 + nt * 16 + r16;
            int row0 = m0 + wr * (BM / 2) + mt * 16 + quad * 4;
            if (MODE == 1 && n0 >= 1024) {
                // V-block: write transposed into vt[bh][d][n]
                int dg = col - 1024, hh = dg >> 6, d = dg & 63;
                int bb = row0 >> 11, n = row0 & 2047;
                bf16x4 o;
#pragma unroll
                for (int r = 0; r < 4; ++r) o[r] = (bf16)acc[mt][nt][r];
                *(bf16x4*)&vtout[((size_t)((bb << 3) | hh) * 64 + d) * 2048 + n] = o;
            } else {
#pragma unroll
                for (int r = 0; r < 4; ++r) {
                    float v = acc[mt][nt][r];
                    if (MODE == 1 && n0 < 512) v *= CS;
                    if (MODE == 2) v += bias[col];
                    C[(size_t)(row0 + r) * N + col] = (OutT)v;
                }
            }
        }
}

// ---------------------------------------------------------------------------
// Flash attention (v8 form, proven 48.4 us round 10): barrier-free per-wave
// streaming, SW-pipelined private double-buffered LDS staging, vmcnt(8)
// counted wait, permlane32_swap bfrag. No setprio (round 9: -2.2 us; no wave
// role-diversity -> prio boosts starve identical twins, matches m190).
// ---------------------------------------------------------------------------
__global__ __launch_bounds__(128, 2) void attn_kernel(const bf16* __restrict__ qkv,
                                                      const bf16* __restrict__ vt,
                                                      bf16* __restrict__ out) {
    __shared__ __align__(16) char smemraw[32768];
    bf16* stage = (bf16*)smemraw;       // [2 waves][2 bufs][4096 elems]

    int t = threadIdx.x;
    int lane = t & 63, w = t >> 6;      // w in {0,1}
    int h = lane >> 5, q = lane & 31;
    int bh = blockIdx.y, b = bh >> 3, hd = bh & 7;
    int qb = blockIdx.x * 64;

    // Q fragments for both subtiles: lane holds Q[qb+sub*32+q][s*16+h*8+j]
    bf16x8 qf[2][4];
#pragma unroll
    for (int sub = 0; sub < 2; ++sub) {
        size_t qoff = (size_t)(b * 2048 + qb + sub * 32 + q) * 1536 + hd * 64;
#pragma unroll
        for (int s = 0; s < 4; ++s)
            qf[sub][s] = *(const bf16x8*)&qkv[qoff + s * 16 + h * 8];
    }

    f32x16 o_acc[2][2];
#pragma unroll
    for (int sub = 0; sub < 2; ++sub)
#pragma unroll
        for (int db = 0; db < 2; ++db)
#pragma unroll
            for (int i = 0; i < 16; ++i) o_acc[sub][db][i] = 0.f;
    float psum[2] = {0.f, 0.f};

    bf16* base = stage + w * 8192;      // this wave's two buffers

    // staging pointers (advance by constant stride) + LDS offsets in-buffer
    const bf16* kp[4]; const bf16* vp[4];
    int kdo[4], vdo[4];
#pragma unroll
    for (int rdd = 0; rdd < 4; ++rdd) {
        int ciK = rdd * 64 + lane;
        int rowK = ciK >> 3, ccK = (ciK & 7) ^ (rowK & 7);
        kp[rdd] = &qkv[(size_t)(b * 2048 + w * 1024 + rowK) * 1536 + 512 + hd * 64 + ccK * 8];
        kdo[rdd] = ciK * 8;
        int ciV = rdd * 64 + lane;
        int rowV = ciV >> 2, ccV = (ciV & 3) ^ (rowV & 3);
        vp[rdd] = &vt[(size_t)(bh * 64 + rowV) * 2048 + w * 1024 + ccV * 8];
        vdo[rdd] = 2048 + ciV * 8;
    }

    // prologue: stage tile 0 into buf 0
#pragma unroll
    for (int rdd = 0; rdd < 4; ++rdd) {
        load_lds16(kp[rdd], base + kdo[rdd]);  kp[rdd] += (size_t)32 * 1536;
        load_lds16(vp[rdd], base + vdo[rdd]);  vp[rdd] += 32;
    }

    for (int it = 0; it < 32; ++it) {
        const bf16* Ks = base + (it & 1) * 4096;   // [32][64]
        const bf16* Vs = Ks + 2048;                // [64][32]
        if (it < 31) {
            bf16* nb = base + ((it + 1) & 1) * 4096;
#pragma unroll
            for (int rdd = 0; rdd < 4; ++rdd) {
                load_lds16(kp[rdd], nb + kdo[rdd]);  kp[rdd] += (size_t)32 * 1536;
                load_lds16(vp[rdd], nb + vdo[rdd]);  vp[rdd] += 32;
            }
            WAIT_VM8();    // tile `it` resident; tile it+1 still in flight
        } else {
            WAIT_VM0();    // final tile resident
        }

        // K fragments (shared by both q-subtiles): A-row m = q (kv-local)
        bf16x8 kf[4];
#pragma unroll
        for (int s = 0; s < 4; ++s) {
            int cp = (s * 2 + h) ^ (q & 7);
            kf[s] = *(const bf16x8*)&Ks[q * 64 + cp * 8];
        }
        // V fragments (shared by both q-subtiles): A-row d = db*32+q
        bf16x8 vf[2][2];
#pragma unroll
        for (int kstep = 0; kstep < 2; ++kstep)
#pragma unroll
            for (int db = 0; db < 2; ++db) {
                int cp = (kstep * 2 + h) ^ (q & 3);
                vf[kstep][db] = *(const bf16x8*)&Vs[(db * 32 + q) * 32 + cp * 8];
            }

#pragma unroll
        for (int sub = 0; sub < 2; ++sub) {
            f32x16 sacc;
#pragma unroll
            for (int i = 0; i < 16; ++i) sacc[i] = 0.f;
#pragma unroll
            for (int s = 0; s < 4; ++s)
                sacc = MFMA32(kf[s], qf[sub][s], sacc);

            // P = exp2(S); psum; build PV B-frags
            bf16x4 pk[4];
            float ps0 = 0.f, ps1 = 0.f, ps2 = 0.f, ps3 = 0.f;
#pragma unroll
            for (int i = 0; i < 4; ++i) {
                float p0 = EXP2(sacc[i]);
                float p1 = EXP2(sacc[4 + i]);
                float p2 = EXP2(sacc[8 + i]);
                float p3 = EXP2(sacc[12 + i]);
                ps0 += p0; ps1 += p1; ps2 += p2; ps3 += p3;
                pk[0][i] = (bf16)p0; pk[1][i] = (bf16)p1;
                pk[2][i] = (bf16)p2; pk[3][i] = (bf16)p3;
            }
            psum[sub] += (ps0 + ps1) + (ps2 + ps3);
            bf16x8 bfr0 = build_bfrag(pk[0], pk[1], h);
            bf16x8 bfr1 = build_bfrag(pk[2], pk[3], h);

            // O^T += V^T . P^T
#pragma unroll
            for (int db = 0; db < 2; ++db) {
                o_acc[sub][db] = MFMA32(vf[0][db], bfr0, o_acc[sub][db]);
                o_acc[sub][db] = MFMA32(vf[1][db], bfr1, o_acc[sub][db]);
            }
        }
    }

    // per-q l for this wave's kv half (sum both lane-halves)
    float l_own[2];
#pragma unroll
    for (int sub = 0; sub < 2; ++sub)
        l_own[sub] = sum_halves(psum[sub]);

    // ---- 2-way merge through LDS (overlays stage buffers; barriered) ----
    __syncthreads();
    float* Of = (float*)smemraw;               // [64 q][68]
    float* Lf = (float*)(smemraw + 17408);     // [64]

    if (w == 1) {
#pragma unroll
        for (int sub = 0; sub < 2; ++sub) {
#pragma unroll
            for (int db = 0; db < 2; ++db)
#pragma unroll
                for (int r = 0; r < 16; ++r) {
                    int d = db * 32 + (r & 3) + 8 * (r >> 2) + 4 * h;
                    Of[(sub * 32 + q) * 68 + d] = o_acc[sub][db][r];
                }
            if (h == 0) Lf[sub * 32 + q] = l_own[sub];
        }
    }
    __syncthreads();
    if (w == 0) {
#pragma unroll
        for (int sub = 0; sub < 2; ++sub) {
#pragma unroll
            for (int db = 0; db < 2; ++db)
#pragma unroll
                for (int r = 0; r < 16; ++r) {
                    int d = db * 32 + (r & 3) + 8 * (r >> 2) + 4 * h;
                    Of[(sub * 32 + q) * 68 + d] += o_acc[sub][db][r];
                }
            if (h == 0) Lf[sub * 32 + q] += l_own[sub];
        }
    }
    __syncthreads();

    // normalize + coalesced store: 128 threads, each 1 half-row (32 elems)
    {
        int row = t >> 1, half = t & 1;
        float linv = 1.f / Lf[row];
        const float* src = &Of[row * 68 + half * 32];
        bf16* dst = &out[(size_t)(b * 2048 + qb + row) * 512 + hd * 64 + half * 32];
#pragma unroll
        for (int i = 0; i < 4; ++i) {
            f32x4 a = *(const f32x4*)&src[i * 8];
            f32x4 c = *(const f32x4*)&src[i * 8 + 4];
            bf16x8 o8;
#pragma unroll
            for (int j = 0; j < 4; ++j) {
                o8[j] = (bf16)(a[j] * linv);
                o8[4 + j] = (bf16)(c[j] * linv);
            }
            *(bf16x8*)&dst[i * 8] = o8;
        }
    }
}

// ---------------------------------------------------------------------------
extern "C" void kernel_launch(void* const* d_in, const int* in_sizes, int n_in,
                              void* d_out, int out_size, void* d_ws, size_t ws_size,
                              hipStream_t stream) {
    const float* x     = (const float*)d_in[0];   // [4*2048][512] f32
    const float* w_qkv = (const float*)d_in[1];   // [512][1536]   f32
    const float* w_out = (const float*)d_in[2];   // [512][512]    f32
    const float* b_out = (const float*)d_in[3];   // [512]         f32
    float* out = (float*)d_out;                   // [4*2048][512] f32

    char* ws = (char*)d_ws;
    size_t off = 0;
    bf16* xb    = (bf16*)(ws + off); off += (size_t)8192 * 512 * 2;        // 8 MB
    bf16* wqkvT = (bf16*)(ws + off); off += (size_t)1536 * 512 * 2;        // 1.5 MB
    bf16* woutT = (bf16*)(ws + off); off += (size_t)512 * 512 * 2;         // 0.5 MB
    bf16* qkv   = (bf16*)(ws + off); off += (size_t)8192 * 1536 * 2;       // 24 MB
    bf16* vt    = (bf16*)(ws + off); off += (size_t)32 * 64 * 2048 * 2;    // 8 MB
    bf16* attn  = (bf16*)(ws + off);                                       // 8 MB

    // fused prep: convert x + both weight transposes
    prep_kernel<<<5120, 256, 0, stream>>>(x, w_qkv, w_out, xb, wqkvT, woutT);
    // QKV GEMM, 128x128 tile, BK=32, TRIPLE-buffered (48KB LDS, 3 blocks/CU
    // grid-capped; 2 tiles in flight); V written directly transposed to vt
    gemm_bt_kernel<4, 32, 3, 1, bf16><<<dim3(12, 64), 256, 0, stream>>>(
        xb, wqkvT, nullptr, qkv, vt, 8192, 1536, 512);
    attn_kernel<<<dim3(32, 32), 128, 0, stream>>>(qkv, vt, attn);
    // out proj, BM=64, BK=64, double-buffered, grid 512, +bias, f32 out
    gemm_bt_kernel<2, 64, 2, 2, float><<<dim3(4, 128), 256, 0, stream>>>(
        attn, woutT, b_out, out, nullptr, 8192, 512, 512);
}